// Round 1
// 599.947 us; speedup vs baseline: 2.8255x; 2.8255x over previous
//
#include <hip/hip_runtime.h>

#define LNEPS 1e-5f

typedef short bf16x8 __attribute__((ext_vector_type(8)));
typedef float f32x4 __attribute__((ext_vector_type(4)));

// ---------------- ws layout (ushort element offsets) ----------------
//   Wq     native [o][dp]            @ 0
//   WkT_f  [dp][o] * lnk_w[dp]       @ 65536
//   Wv_f   native [o][dp] * lnv_w    @ 131072
//   Wp hi  native                    @ 196608
//   W1     native                    @ 262144
//   W2     native                    @ 393216
//   Wp lo  native                    @ 524288
//   bva    fp32[256] (bv + Wv.lnv_b) @ 589824 (ush offset; 512 ush)
//   T      bf16 [8192][2048]         @ 590336
//   a      fp32 [8192][256]          @ 17367552 (ush offset)
#define WQ_OFF    0
#define WKT_OFF   65536
#define WV_OFF    131072
#define WPHI_OFF  196608
#define W1_OFF    262144
#define W2_OFF    393216
#define WPLO_OFF  524288
#define BVA_OFF   589824
#define T_OFF     590336
#define AG_OFF    17367552

__device__ __forceinline__ unsigned short f2bf(float f) {
    union { float f; unsigned int u; } a; a.f = f;
    unsigned int u = a.u;
    unsigned int r = (u + 0x7fffu + ((u >> 16) & 1u)) >> 16;
    return (unsigned short)r;
}
__device__ __forceinline__ float bf2f(unsigned short h) {
    union { unsigned int u; float f; } a; a.u = ((unsigned int)h) << 16;
    return a.f;
}

__device__ __forceinline__ void rowstats(float4 v, float& mu, float& inv) {
    float s  = v.x + v.y + v.z + v.w;
    float ss = v.x * v.x + v.y * v.y + v.z * v.z + v.w * v.w;
    #pragma unroll
    for (int off = 32; off; off >>= 1) {
        s  += __shfl_xor(s, off);
        ss += __shfl_xor(ss, off);
    }
    mu  = s * (1.f / 256.f);
    float var = ss * (1.f / 256.f) - mu * mu;
    inv = rsqrtf(fmaxf(var, 0.f) + LNEPS);
}

// ---------------- prep: bf16 weights with LN-weight folds ----------------
__global__ void prep_weights(const float* __restrict__ Wq, const float* __restrict__ Wk,
                             const float* __restrict__ Wv, const float* __restrict__ Wp,
                             const float* __restrict__ W1, const float* __restrict__ W2,
                             const float* __restrict__ lnk_w, const float* __restrict__ lnv_w,
                             unsigned short* __restrict__ ws) {
    int i = blockIdx.x * 256 + threadIdx.x;
    if (i < 65536)       { ws[i] = f2bf(Wq[i]); }
    else if (i < 131072) { int l = i - 65536; int dp = l >> 8, o = l & 255;
                           ws[i] = f2bf(Wk[o * 256 + dp] * lnk_w[dp]); }
    else if (i < 196608) { int l = i - 131072; int dp = l & 255;
                           ws[i] = f2bf(Wv[l] * lnv_w[dp]); }
    else if (i < 262144) { ws[i] = f2bf(Wp[i - 196608]); }
    else if (i < 393216) { ws[i] = f2bf(W1[i - 262144]); }
    else if (i < 524288) { ws[i] = f2bf(W2[i - 393216]); }
    else if (i < 589824) { float w = Wp[i - 524288]; ws[i] = f2bf(w - bf2f(f2bf(w))); }
}

// bva[o] = bv[o] + sum_dp Wv[o][dp]*lnv_b[dp]   (exact since sum_n p = 1)
__global__ void prep_bias(const float* __restrict__ Wv, const float* __restrict__ lnv_b,
                          const float* __restrict__ bv, float* __restrict__ bva) {
    int o = threadIdx.x;
    float acc = bv[o];
    #pragma unroll 4
    for (int dp = 0; dp < 256; dp += 4) {
        float4 w = *(const float4*)(Wv + o * 256 + dp);
        float4 g = *(const float4*)(lnv_b + dp);
        acc += w.x * g.x + w.y * g.y + w.z * g.z + w.w * g.w;
    }
    bva[o] = acc;
}

// ---------------- kernel A: LN(x) -> q' -> T = q' @ WkT_f (MFMA) ----------------
__global__ __launch_bounds__(256, 2)
void qt_kernel(const float* __restrict__ x,
               const float* __restrict__ lnq_w, const float* __restrict__ lnq_b,
               const float* __restrict__ bq,
               const unsigned short* __restrict__ wsb, unsigned short* __restrict__ Tg) {
    const int tid  = threadIdx.x;
    const int lane = tid & 63;
    const int wid  = tid >> 6;
    const int q4   = lane >> 4;
    const int l16  = lane & 15;
    const int b    = blockIdx.x >> 8;
    const int m0   = (blockIdx.x & 255) * 16;
    const float scale = 0.17677669529663687f; // 1/sqrt(32)

    const unsigned short* Wq_bf  = wsb + WQ_OFF;
    const unsigned short* WkT_bf = wsb + WKT_OFF;

    __shared__ __align__(16) unsigned short lnX[16][264];
    __shared__ __align__(16) unsigned short sQ[16][264];

    // P1: layernorm(x) -> lnX (bf16, lnq affine)
    {
        const float4 w4 = *(const float4*)(lnq_w + lane * 4);
        const float4 g4 = *(const float4*)(lnq_b + lane * 4);
        float4 xv[4];
        #pragma unroll
        for (int rr = 0; rr < 4; rr++) {
            int m = wid * 4 + rr;
            xv[rr] = *(const float4*)(x + (size_t)(b * 4096 + m0 + m) * 256 + lane * 4);
        }
        #pragma unroll
        for (int rr = 0; rr < 4; rr++) {
            int m = wid * 4 + rr;
            float mu, inv; rowstats(xv[rr], mu, inv);
            float4 v = xv[rr];
            ushort4 o;
            o.x = f2bf((v.x - mu) * inv * w4.x + g4.x);
            o.y = f2bf((v.y - mu) * inv * w4.y + g4.y);
            o.z = f2bf((v.z - mu) * inv * w4.z + g4.z);
            o.w = f2bf((v.w - mu) * inv * w4.w + g4.w);
            *(ushort4*)&lnX[m][lane * 4] = o;
        }
    }
    __syncthreads();

    // P2: q' = (lnX @ Wq^T + bq) * scale -> sQ (bf16)
    {
        f32x4 acc[4];
        #pragma unroll
        for (int j = 0; j < 4; j++) acc[j] = 0.f;
        #pragma unroll
        for (int k = 0; k < 8; k++) {
            bf16x8 af = *(const bf16x8*)&lnX[l16][k * 32 + q4 * 8];
            #pragma unroll
            for (int j = 0; j < 4; j++) {
                int o = wid * 64 + j * 16 + l16;
                bf16x8 bfv = *(const bf16x8*)(Wq_bf + o * 256 + k * 32 + q4 * 8);
                acc[j] = __builtin_amdgcn_mfma_f32_16x16x32_bf16(af, bfv, acc[j], 0, 0, 0);
            }
        }
        #pragma unroll
        for (int j = 0; j < 4; j++) {
            int o = wid * 64 + j * 16 + l16;
            float bqv = bq[o];
            #pragma unroll
            for (int r = 0; r < 4; r++) {
                sQ[q4 * 4 + r][o] = f2bf((acc[j][r] + bqv) * scale);
            }
        }
    }
    __syncthreads();

    // T[m][h][dp] = sum_d q'[m][h*32+d] * WkT_f[dp][h*32+d]  (one MFMA per (h, dp-tile))
    {
        const size_t rowbase = (size_t)(b * 4096 + m0) * 2048;
        #pragma unroll
        for (int h = 0; h < 8; h++) {
            bf16x8 af = *(const bf16x8*)&sQ[l16][h * 32 + q4 * 8];
            #pragma unroll
            for (int t = 0; t < 4; t++) {
                const int dp0 = (wid * 4 + t) * 16;
                bf16x8 bfv = *(const bf16x8*)(WkT_bf + (size_t)(dp0 + l16) * 256 + h * 32 + q4 * 8);
                f32x4 acc = {0.f, 0.f, 0.f, 0.f};
                acc = __builtin_amdgcn_mfma_f32_16x16x32_bf16(af, bfv, acc, 0, 0, 0);
                #pragma unroll
                for (int r = 0; r < 4; r++) {
                    int ml = q4 * 4 + r;
                    Tg[rowbase + (size_t)ml * 2048 + h * 256 + dp0 + l16] = f2bf(acc[r]);
                }
            }
        }
    }
}

// ---------------- kernel B: per-m-row attention ----------------
// grid = 8192 blocks (one per (b,m)); 4 waves; ~34.5 KB LDS -> 4 blocks/CU.
__global__ __launch_bounds__(256, 4)
void attn_kernel(const float* __restrict__ y,
                 const unsigned short* __restrict__ wsb,
                 float* __restrict__ ag) {
    const int tid  = threadIdx.x;
    const int lane = tid & 63;
    const int wid  = tid >> 6;
    const int r    = blockIdx.x;                 // b*4096 + m

    const unsigned short* Wv_bf = wsb + WV_OFF;
    const unsigned short* Tg    = wsb + T_OFF;
    const float*          bva   = (const float*)(wsb + BVA_OFF);

    __shared__ __align__(16) unsigned short Y[32][264];  // normalized y (no affine)
    __shared__ __align__(16) float Tl[8][260];           // T row, fp32
    __shared__ __align__(16) float Usm[8][260];          // u[h][dp]
    __shared__ __align__(16) float sP[32][8];            // logits -> probs

    // load T row (4 KB) -> fp32 LDS
    {
        bf16x8 t8 = *(const bf16x8*)(Tg + (size_t)r * 2048 + tid * 8);
        const int h = tid >> 5, d0 = (tid & 31) * 8;
        #pragma unroll
        for (int j = 0; j < 8; j++) Tl[h][d0 + j] = bf2f((unsigned short)t8[j]);
    }
    // load y (32 KB) + LN -> Y (each wave does 8 rows)
    {
        const float* yb = y + (size_t)r * 8192;
        float4 vv[8];
        #pragma unroll
        for (int u = 0; u < 8; u++) {
            int n = wid * 8 + u;
            vv[u] = *(const float4*)(yb + n * 256 + lane * 4);
        }
        #pragma unroll
        for (int u = 0; u < 8; u++) {
            int n = wid * 8 + u;
            float mu, inv; rowstats(vv[u], mu, inv);
            float4 v = vv[u];
            ushort4 o;
            o.x = f2bf((v.x - mu) * inv);
            o.y = f2bf((v.y - mu) * inv);
            o.z = f2bf((v.z - mu) * inv);
            o.w = f2bf((v.w - mu) * inv);
            *(ushort4*)&Y[n][lane * 4] = o;
        }
    }
    __syncthreads();

    // logits[n][h] = Y[n] . Tl[h]   (thread -> (n = tid>>3, h = tid&7))
    {
        const int n = tid >> 3, h = tid & 7;
        float acc = 0.f;
        #pragma unroll 8
        for (int dv = 0; dv < 32; dv++) {
            bf16x8 y8 = *(const bf16x8*)&Y[n][dv * 8];
            float4 ta = *(const float4*)&Tl[h][dv * 8];
            float4 tb = *(const float4*)&Tl[h][dv * 8 + 4];
            acc += bf2f((unsigned short)y8[0]) * ta.x;
            acc += bf2f((unsigned short)y8[1]) * ta.y;
            acc += bf2f((unsigned short)y8[2]) * ta.z;
            acc += bf2f((unsigned short)y8[3]) * ta.w;
            acc += bf2f((unsigned short)y8[4]) * tb.x;
            acc += bf2f((unsigned short)y8[5]) * tb.y;
            acc += bf2f((unsigned short)y8[6]) * tb.z;
            acc += bf2f((unsigned short)y8[7]) * tb.w;
        }
        sP[n][h] = acc;
    }
    __syncthreads();

    // softmax over n (thread -> (h = tid>>5, n = tid&31); shuffles stay in 32-lane half)
    {
        const int h = tid >> 5, n = tid & 31;
        float v = sP[n][h];
        float mx = v;
        #pragma unroll
        for (int off = 16; off; off >>= 1) mx = fmaxf(mx, __shfl_xor(mx, off));
        float e = __expf(v - mx);
        float s = e;
        #pragma unroll
        for (int off = 16; off; off >>= 1) s += __shfl_xor(s, off);
        sP[n][h] = e / s;
    }
    __syncthreads();

    // u[h][dp] = sum_n p[n][h] * Y[n][dp]   (thread -> dp)
    {
        const int dp = tid;
        float acc[8];
        #pragma unroll
        for (int h = 0; h < 8; h++) acc[h] = 0.f;
        #pragma unroll 8
        for (int n = 0; n < 32; n++) {
            float yv = bf2f(Y[n][dp]);
            float4 pA = *(const float4*)&sP[n][0];
            float4 pB = *(const float4*)&sP[n][4];
            acc[0] += pA.x * yv; acc[1] += pA.y * yv;
            acc[2] += pA.z * yv; acc[3] += pA.w * yv;
            acc[4] += pB.x * yv; acc[5] += pB.y * yv;
            acc[6] += pB.z * yv; acc[7] += pB.w * yv;
        }
        #pragma unroll
        for (int h = 0; h < 8; h++) Usm[h][dp] = acc[h];
    }
    __syncthreads();

    // a[o] = sum_dp Wv_f[o][dp] * u[h(o)][dp] + bva[o]   (thread -> o; Wv L2-hot)
    {
        const int o = tid, h = o >> 5;
        float acc = 0.f;
        #pragma unroll 8
        for (int dpv = 0; dpv < 32; dpv++) {
            bf16x8 wv8 = *(const bf16x8*)(Wv_bf + (size_t)o * 256 + dpv * 8);
            float4 ua = *(const float4*)&Usm[h][dpv * 8];
            float4 ub = *(const float4*)&Usm[h][dpv * 8 + 4];
            acc += bf2f((unsigned short)wv8[0]) * ua.x;
            acc += bf2f((unsigned short)wv8[1]) * ua.y;
            acc += bf2f((unsigned short)wv8[2]) * ua.z;
            acc += bf2f((unsigned short)wv8[3]) * ua.w;
            acc += bf2f((unsigned short)wv8[4]) * ub.x;
            acc += bf2f((unsigned short)wv8[5]) * ub.y;
            acc += bf2f((unsigned short)wv8[6]) * ub.z;
            acc += bf2f((unsigned short)wv8[7]) * ub.w;
        }
        ag[(size_t)r * 256 + o] = acc + bva[o];
    }
}

// ---------------- kernel C: z-proj, LN, FFN, residual, final LN ----------------
__global__ __launch_bounds__(256, 2)
void tail_kernel(const float* __restrict__ ag,
                 const float* __restrict__ bp,
                 const float* __restrict__ pre_w, const float* __restrict__ pre_b,
                 const float* __restrict__ b1, const float* __restrict__ b2,
                 const float* __restrict__ post_w, const float* __restrict__ post_b,
                 const unsigned short* __restrict__ wsb,
                 float* __restrict__ out) {
    const int tid  = threadIdx.x;
    const int lane = tid & 63;
    const int wid  = tid >> 6;
    const int q4   = lane >> 4;
    const int l16  = lane & 15;
    const int b    = blockIdx.x >> 8;
    const int m0   = (blockIdx.x & 255) * 16;

    const unsigned short* Wp_bf   = wsb + WPHI_OFF;
    const unsigned short* W1_bf   = wsb + W1_OFF;
    const unsigned short* W2_bf   = wsb + W2_OFF;
    const unsigned short* Wplo_bf = wsb + WPLO_OFF;

    __shared__ __align__(16) float Z[16][260];
    __shared__ __align__(16) unsigned short G[16][520];
    __shared__ __align__(16) unsigned short sQ[16][264];
    __shared__ __align__(16) float sAf[16][260];

    // load a
    #pragma unroll
    for (int rr = 0; rr < 4; rr++) {
        int m = wid * 4 + rr;
        *(float4*)&sAf[m][lane * 4] =
            *(const float4*)(ag + (size_t)(b * 4096 + m0 + m) * 256 + lane * 4);
    }
    __syncthreads();

    // z = sAf @ Wp^T + bp (hi/lo split for accuracy)
    {
        f32x4 acc[4];
        #pragma unroll
        for (int j = 0; j < 4; j++) acc[j] = 0.f;
        #pragma unroll
        for (int k = 0; k < 8; k++) {
            float4 va = *(const float4*)&sAf[l16][k * 32 + q4 * 8];
            float4 vb = *(const float4*)&sAf[l16][k * 32 + q4 * 8 + 4];
            float vs[8] = {va.x, va.y, va.z, va.w, vb.x, vb.y, vb.z, vb.w};
            bf16x8 ah, al;
            #pragma unroll
            for (int j = 0; j < 8; j++) {
                unsigned short hi = f2bf(vs[j]);
                ah[j] = (short)hi;
                al[j] = (short)f2bf(vs[j] - bf2f(hi));
            }
            #pragma unroll
            for (int j = 0; j < 4; j++) {
                int o = wid * 64 + j * 16 + l16;
                bf16x8 bh = *(const bf16x8*)(Wp_bf   + o * 256 + k * 32 + q4 * 8);
                bf16x8 bl = *(const bf16x8*)(Wplo_bf + o * 256 + k * 32 + q4 * 8);
                acc[j] = __builtin_amdgcn_mfma_f32_16x16x32_bf16(ah, bh, acc[j], 0, 0, 0);
                acc[j] = __builtin_amdgcn_mfma_f32_16x16x32_bf16(al, bh, acc[j], 0, 0, 0);
                acc[j] = __builtin_amdgcn_mfma_f32_16x16x32_bf16(ah, bl, acc[j], 0, 0, 0);
            }
        }
        #pragma unroll
        for (int j = 0; j < 4; j++) {
            int o = wid * 64 + j * 16 + l16;
            float bpv = bp[o];
            #pragma unroll
            for (int r = 0; r < 4; r++) Z[q4 * 4 + r][o] = acc[j][r] + bpv;
        }
    }
    __syncthreads();
    // pre-LN: normalize Z in place (residual base) + bf16 copy in sQ
    {
        const float4 w4 = *(const float4*)(pre_w + lane * 4);
        const float4 g4 = *(const float4*)(pre_b + lane * 4);
        #pragma unroll
        for (int rr = 0; rr < 4; rr++) {
            int m = wid * 4 + rr;
            float4 v = *(const float4*)&Z[m][lane * 4];
            float mu, inv; rowstats(v, mu, inv);
            float4 z;
            z.x = (v.x - mu) * inv * w4.x + g4.x;
            z.y = (v.y - mu) * inv * w4.y + g4.y;
            z.z = (v.z - mu) * inv * w4.z + g4.z;
            z.w = (v.w - mu) * inv * w4.w + g4.w;
            *(float4*)&Z[m][lane * 4] = z;
            ushort4 o;
            o.x = f2bf(z.x); o.y = f2bf(z.y); o.z = f2bf(z.z); o.w = f2bf(z.w);
            *(ushort4*)&sQ[m][lane * 4] = o;
        }
    }
    __syncthreads();
    // FFN1 + exact gelu -> G
    {
        f32x4 acc[8];
        #pragma unroll
        for (int j = 0; j < 8; j++) acc[j] = 0.f;
        #pragma unroll
        for (int k = 0; k < 8; k++) {
            bf16x8 af = *(const bf16x8*)&sQ[l16][k * 32 + q4 * 8];
            #pragma unroll
            for (int j = 0; j < 8; j++) {
                int f = wid * 128 + j * 16 + l16;
                bf16x8 bfv = *(const bf16x8*)(W1_bf + f * 256 + k * 32 + q4 * 8);
                acc[j] = __builtin_amdgcn_mfma_f32_16x16x32_bf16(af, bfv, acc[j], 0, 0, 0);
            }
        }
        #pragma unroll
        for (int j = 0; j < 8; j++) {
            int f = wid * 128 + j * 16 + l16;
            float b1v = b1[f];
            #pragma unroll
            for (int r = 0; r < 4; r++) {
                float vz = acc[j][r] + b1v;
                float g = 0.5f * vz * (1.f + erff(vz * 0.7071067811865475f));
                G[q4 * 4 + r][f] = f2bf(g);
            }
        }
    }
    __syncthreads();
    // FFN2 + residual -> Z
    {
        f32x4 acc[4];
        #pragma unroll
        for (int j = 0; j < 4; j++) acc[j] = 0.f;
        #pragma unroll
        for (int k = 0; k < 16; k++) {
            bf16x8 af = *(const bf16x8*)&G[l16][k * 32 + q4 * 8];
            #pragma unroll
            for (int j = 0; j < 4; j++) {
                int o = wid * 64 + j * 16 + l16;
                bf16x8 bfv = *(const bf16x8*)(W2_bf + o * 512 + k * 32 + q4 * 8);
                acc[j] = __builtin_amdgcn_mfma_f32_16x16x32_bf16(af, bfv, acc[j], 0, 0, 0);
            }
        }
        #pragma unroll
        for (int j = 0; j < 4; j++) {
            int o = wid * 64 + j * 16 + l16;
            float b2v = b2[o];
            #pragma unroll
            for (int r = 0; r < 4; r++) Z[q4 * 4 + r][o] += acc[j][r] + b2v;
        }
    }
    __syncthreads();
    // final LN -> out
    {
        const float4 w4 = *(const float4*)(post_w + lane * 4);
        const float4 g4 = *(const float4*)(post_b + lane * 4);
        #pragma unroll
        for (int rr = 0; rr < 4; rr++) {
            int m = wid * 4 + rr;
            float4 v = *(const float4*)&Z[m][lane * 4];
            float mu, inv; rowstats(v, mu, inv);
            float4 o;
            o.x = (v.x - mu) * inv * w4.x + g4.x;
            o.y = (v.y - mu) * inv * w4.y + g4.y;
            o.z = (v.z - mu) * inv * w4.z + g4.z;
            o.w = (v.w - mu) * inv * w4.w + g4.w;
            *(float4*)(out + (size_t)(b * 4096 + m0 + m) * 256 + lane * 4) = o;
        }
    }
}

extern "C" void kernel_launch(void* const* d_in, const int* in_sizes, int n_in,
                              void* d_out, int out_size, void* d_ws, size_t ws_size,
                              hipStream_t stream) {
    (void)in_sizes; (void)n_in; (void)out_size; (void)ws_size;
    const float* x      = (const float*)d_in[0];
    const float* y      = (const float*)d_in[1];
    const float* lnq_w  = (const float*)d_in[2];
    const float* lnq_b  = (const float*)d_in[3];
    const float* Wq     = (const float*)d_in[4];
    const float* bq     = (const float*)d_in[5];
    const float* lnk_w  = (const float*)d_in[6];
    // d_in[7] = lnk_b : softmax-invariant (dropped)
    const float* Wk     = (const float*)d_in[8];
    // d_in[9] = bk : softmax-invariant (dropped)
    const float* lnv_w  = (const float*)d_in[10];
    const float* lnv_b  = (const float*)d_in[11];
    const float* Wv     = (const float*)d_in[12];
    const float* bv     = (const float*)d_in[13];
    const float* Wp     = (const float*)d_in[14];
    const float* bp     = (const float*)d_in[15];
    const float* pre_w  = (const float*)d_in[16];
    const float* pre_b  = (const float*)d_in[17];
    const float* W1     = (const float*)d_in[18];
    const float* b1     = (const float*)d_in[19];
    const float* W2     = (const float*)d_in[20];
    const float* b2     = (const float*)d_in[21];
    const float* post_w = (const float*)d_in[22];
    const float* post_b = (const float*)d_in[23];
    unsigned short* wsb = (unsigned short*)d_ws;
    float* bva = (float*)(wsb + BVA_OFF);
    unsigned short* Tg = wsb + T_OFF;
    float* ag = (float*)(wsb + AG_OFF);

    prep_weights<<<2304, 256, 0, stream>>>(Wq, Wk, Wv, Wp, W1, W2, lnk_w, lnv_w, wsb);
    prep_bias<<<1, 256, 0, stream>>>(Wv, lnv_b, bv, bva);
    qt_kernel<<<512, 256, 0, stream>>>(x, lnq_w, lnq_b, bq, wsb, Tg);
    attn_kernel<<<8192, 256, 0, stream>>>(y, wsb, ag);
    tail_kernel<<<512, 256, 0, stream>>>(ag, bp, pre_w, pre_b, b1, b2, post_w, post_b,
                                         wsb, (float*)d_out);
}

// Round 4
// 594.638 us; speedup vs baseline: 2.8507x; 1.0089x over previous
//
#include <hip/hip_runtime.h>

#define LNEPS 1e-5f

typedef short bf16x8 __attribute__((ext_vector_type(8)));
typedef float f32x4 __attribute__((ext_vector_type(4)));

// ---------------- ws layout (ushort element offsets) ----------------
#define WQ_OFF    0
#define WKT_OFF   65536
#define WV_OFF    131072
#define WPHI_OFF  196608
#define W1_OFF    262144
#define W2_OFF    393216
#define WPLO_OFF  524288
#define BVA_OFF   589824
#define T_OFF     590336
#define AG_OFF    17367552

__device__ __forceinline__ unsigned short f2bf(float f) {
    union { float f; unsigned int u; } a; a.f = f;
    unsigned int u = a.u;
    unsigned int r = (u + 0x7fffu + ((u >> 16) & 1u)) >> 16;
    return (unsigned short)r;
}
__device__ __forceinline__ float bf2f(unsigned short h) {
    union { unsigned int u; float f; } a; a.u = ((unsigned int)h) << 16;
    return a.f;
}

__device__ __forceinline__ void rowstats(float4 v, float& mu, float& inv) {
    float s  = v.x + v.y + v.z + v.w;
    float ss = v.x * v.x + v.y * v.y + v.z * v.z + v.w * v.w;
    #pragma unroll
    for (int off = 32; off; off >>= 1) {
        s  += __shfl_xor(s, off);
        ss += __shfl_xor(ss, off);
    }
    mu  = s * (1.f / 256.f);
    float var = ss * (1.f / 256.f) - mu * mu;
    inv = rsqrtf(fmaxf(var, 0.f) + LNEPS);
}

// ---------------- prep: bf16 weights with LN-weight folds ----------------
__global__ void prep_weights(const float* __restrict__ Wq, const float* __restrict__ Wk,
                             const float* __restrict__ Wv, const float* __restrict__ Wp,
                             const float* __restrict__ W1, const float* __restrict__ W2,
                             const float* __restrict__ lnk_w, const float* __restrict__ lnv_w,
                             unsigned short* __restrict__ ws) {
    int i = blockIdx.x * 256 + threadIdx.x;
    if (i < 65536)       { ws[i] = f2bf(Wq[i]); }
    else if (i < 131072) { int l = i - 65536; int dp = l >> 8, o = l & 255;
                           ws[i] = f2bf(Wk[o * 256 + dp] * lnk_w[dp]); }
    else if (i < 196608) { int l = i - 131072; int dp = l & 255;
                           ws[i] = f2bf(Wv[l] * lnv_w[dp]); }
    else if (i < 262144) { ws[i] = f2bf(Wp[i - 196608]); }
    else if (i < 393216) { ws[i] = f2bf(W1[i - 262144]); }
    else if (i < 524288) { ws[i] = f2bf(W2[i - 393216]); }
    else if (i < 589824) { float w = Wp[i - 524288]; ws[i] = f2bf(w - bf2f(f2bf(w))); }
}

// bva[o] = bv[o] + sum_dp Wv[o][dp]*lnv_b[dp]   (exact since sum_n p = 1)
__global__ void prep_bias(const float* __restrict__ Wv, const float* __restrict__ lnv_b,
                          const float* __restrict__ bv, float* __restrict__ bva) {
    int o = threadIdx.x;
    float acc = bv[o];
    #pragma unroll 4
    for (int dp = 0; dp < 256; dp += 4) {
        float4 w = *(const float4*)(Wv + o * 256 + dp);
        float4 g = *(const float4*)(lnv_b + dp);
        acc += w.x * g.x + w.y * g.y + w.z * g.z + w.w * g.w;
    }
    bva[o] = acc;
}

// ---------------- kernel A: LN(x) -> q' -> T = q' @ WkT_f (MFMA) ----------------
__global__ __launch_bounds__(256, 2)
void qt_kernel(const float* __restrict__ x,
               const float* __restrict__ lnq_w, const float* __restrict__ lnq_b,
               const float* __restrict__ bq,
               const unsigned short* __restrict__ wsb, unsigned short* __restrict__ Tg) {
    const int tid  = threadIdx.x;
    const int lane = tid & 63;
    const int wid  = tid >> 6;
    const int q4   = lane >> 4;
    const int l16  = lane & 15;
    const int b    = blockIdx.x >> 8;
    const int m0   = (blockIdx.x & 255) * 16;
    const float scale = 0.17677669529663687f; // 1/sqrt(32)

    const unsigned short* Wq_bf  = wsb + WQ_OFF;
    const unsigned short* WkT_bf = wsb + WKT_OFF;

    __shared__ __align__(16) unsigned short lnX[16][264];
    __shared__ __align__(16) unsigned short sQ[16][264];

    // P1: layernorm(x) -> lnX (bf16, lnq affine)
    {
        const float4 w4 = *(const float4*)(lnq_w + lane * 4);
        const float4 g4 = *(const float4*)(lnq_b + lane * 4);
        float4 xv[4];
        #pragma unroll
        for (int rr = 0; rr < 4; rr++) {
            int m = wid * 4 + rr;
            xv[rr] = *(const float4*)(x + (size_t)(b * 4096 + m0 + m) * 256 + lane * 4);
        }
        #pragma unroll
        for (int rr = 0; rr < 4; rr++) {
            int m = wid * 4 + rr;
            float mu, inv; rowstats(xv[rr], mu, inv);
            float4 v = xv[rr];
            ushort4 o;
            o.x = f2bf((v.x - mu) * inv * w4.x + g4.x);
            o.y = f2bf((v.y - mu) * inv * w4.y + g4.y);
            o.z = f2bf((v.z - mu) * inv * w4.z + g4.z);
            o.w = f2bf((v.w - mu) * inv * w4.w + g4.w);
            *(ushort4*)&lnX[m][lane * 4] = o;
        }
    }
    __syncthreads();

    // P2: q' = (lnX @ Wq^T + bq) * scale -> sQ (bf16)
    {
        f32x4 acc[4];
        #pragma unroll
        for (int j = 0; j < 4; j++) acc[j] = 0.f;
        #pragma unroll
        for (int k = 0; k < 8; k++) {
            bf16x8 af = *(const bf16x8*)&lnX[l16][k * 32 + q4 * 8];
            #pragma unroll
            for (int j = 0; j < 4; j++) {
                int o = wid * 64 + j * 16 + l16;
                bf16x8 bfv = *(const bf16x8*)(Wq_bf + o * 256 + k * 32 + q4 * 8);
                acc[j] = __builtin_amdgcn_mfma_f32_16x16x32_bf16(af, bfv, acc[j], 0, 0, 0);
            }
        }
        #pragma unroll
        for (int j = 0; j < 4; j++) {
            int o = wid * 64 + j * 16 + l16;
            float bqv = bq[o];
            #pragma unroll
            for (int r = 0; r < 4; r++) {
                sQ[q4 * 4 + r][o] = f2bf((acc[j][r] + bqv) * scale);
            }
        }
    }
    __syncthreads();

    // T[m][h][dp] = sum_d q'[m][h*32+d] * WkT_f[dp][h*32+d]
    {
        const size_t rowbase = (size_t)(b * 4096 + m0) * 2048;
        #pragma unroll
        for (int h = 0; h < 8; h++) {
            bf16x8 af = *(const bf16x8*)&sQ[l16][h * 32 + q4 * 8];
            #pragma unroll
            for (int t = 0; t < 4; t++) {
                const int dp0 = (wid * 4 + t) * 16;
                bf16x8 bfv = *(const bf16x8*)(WkT_bf + (size_t)(dp0 + l16) * 256 + h * 32 + q4 * 8);
                f32x4 acc = {0.f, 0.f, 0.f, 0.f};
                acc = __builtin_amdgcn_mfma_f32_16x16x32_bf16(af, bfv, acc, 0, 0, 0);
                #pragma unroll
                for (int r = 0; r < 4; r++) {
                    int ml = q4 * 4 + r;
                    Tg[rowbase + (size_t)ml * 2048 + h * 256 + dp0 + l16] = f2bf(acc[r]);
                }
            }
        }
    }
}

// ---------------- kernel B: per-m-row attention ----------------
// grid = 8192 blocks (one per (b,m)); 4 waves; ~26.4 KB LDS.
// logits: scalar fp32 (verified R1 path). V = Y@Wv^T via MFMA (acc in regs),
// a[o] = sum_n P[n][h(o)]*V[n][o] reduced in-register + q4-butterfly.
__global__ __launch_bounds__(256, 4)
void attn_kernel(const float* __restrict__ y,
                 const unsigned short* __restrict__ wsb,
                 float* __restrict__ ag) {
    const int tid  = threadIdx.x;
    const int lane = tid & 63;
    const int wid  = tid >> 6;
    const int q4   = lane >> 4;
    const int l16  = lane & 15;
    const int r    = blockIdx.x;                 // b*4096 + m

    const unsigned short* Wv_bf = wsb + WV_OFF;
    const unsigned short* Tg    = wsb + T_OFF;
    const float*          bva   = (const float*)(wsb + BVA_OFF);

    __shared__ __align__(16) unsigned short Y[32][264];  // normalized y (no affine)
    __shared__ __align__(16) float Tl[8][260];           // T row, fp32
    __shared__ __align__(16) float sP[32][9];            // logits -> probs

    // load T row (4 KB) -> fp32 LDS
    {
        bf16x8 t8 = *(const bf16x8*)(Tg + (size_t)r * 2048 + tid * 8);
        const int h = tid >> 5, d0 = (tid & 31) * 8;
        #pragma unroll
        for (int j = 0; j < 8; j++) Tl[h][d0 + j] = bf2f((unsigned short)t8[j]);
    }
    // load y (32 KB) + LN -> Y (each wave does 8 rows)
    {
        const float* yb = y + (size_t)r * 8192;
        float4 vv[8];
        #pragma unroll
        for (int u = 0; u < 8; u++) {
            int n = wid * 8 + u;
            vv[u] = *(const float4*)(yb + n * 256 + lane * 4);
        }
        #pragma unroll
        for (int u = 0; u < 8; u++) {
            int n = wid * 8 + u;
            float mu, inv; rowstats(vv[u], mu, inv);
            float4 v = vv[u];
            ushort4 o;
            o.x = f2bf((v.x - mu) * inv);
            o.y = f2bf((v.y - mu) * inv);
            o.z = f2bf((v.z - mu) * inv);
            o.w = f2bf((v.w - mu) * inv);
            *(ushort4*)&Y[n][lane * 4] = o;
        }
    }
    __syncthreads();

    // V[n][o] = Y[n] . Wv_f[o]  (MFMA; acc stays in registers)
    // wave w owns o = w*64 .. w*64+63 (4 o-tiles), both n-tiles.
    f32x4 vacc[2][4];
    #pragma unroll
    for (int nt = 0; nt < 2; nt++)
        #pragma unroll
        for (int j = 0; j < 4; j++) vacc[nt][j] = 0.f;
    #pragma unroll
    for (int k = 0; k < 8; k++) {
        bf16x8 a0 = *(const bf16x8*)&Y[l16][k * 32 + q4 * 8];
        bf16x8 a1 = *(const bf16x8*)&Y[16 + l16][k * 32 + q4 * 8];
        #pragma unroll
        for (int j = 0; j < 4; j++) {
            int o = wid * 64 + j * 16 + l16;
            bf16x8 bv8 = *(const bf16x8*)(Wv_bf + (size_t)o * 256 + k * 32 + q4 * 8);
            vacc[0][j] = __builtin_amdgcn_mfma_f32_16x16x32_bf16(a0, bv8, vacc[0][j], 0, 0, 0);
            vacc[1][j] = __builtin_amdgcn_mfma_f32_16x16x32_bf16(a1, bv8, vacc[1][j], 0, 0, 0);
        }
    }

    // logits[n][h] = Y[n] . Tl[h]   (scalar fp32, verified; thread -> (n=tid>>3, h=tid&7))
    {
        const int n = tid >> 3, h = tid & 7;
        float acc = 0.f;
        #pragma unroll 8
        for (int dv = 0; dv < 32; dv++) {
            bf16x8 y8 = *(const bf16x8*)&Y[n][dv * 8];
            float4 ta = *(const float4*)&Tl[h][dv * 8];
            float4 tb = *(const float4*)&Tl[h][dv * 8 + 4];
            acc += bf2f((unsigned short)y8[0]) * ta.x;
            acc += bf2f((unsigned short)y8[1]) * ta.y;
            acc += bf2f((unsigned short)y8[2]) * ta.z;
            acc += bf2f((unsigned short)y8[3]) * ta.w;
            acc += bf2f((unsigned short)y8[4]) * tb.x;
            acc += bf2f((unsigned short)y8[5]) * tb.y;
            acc += bf2f((unsigned short)y8[6]) * tb.z;
            acc += bf2f((unsigned short)y8[7]) * tb.w;
        }
        sP[n][h] = acc;
    }
    __syncthreads();

    // softmax over n (thread -> (h = tid>>5, n = tid&31))
    {
        const int h = tid >> 5, n = tid & 31;
        float v = sP[n][h];
        float mx = v;
        #pragma unroll
        for (int off = 16; off; off >>= 1) mx = fmaxf(mx, __shfl_xor(mx, off));
        float e = __expf(v - mx);
        float s = e;
        #pragma unroll
        for (int off = 16; off; off >>= 1) s += __shfl_xor(s, off);
        sP[n][h] = e / s;
    }
    __syncthreads();

    // a[o] = sum_n P[n][h(o)] * V[n][o] + bva[o]
    // lane holds V rows n in {q4*4+idx, 16+q4*4+idx}; butterfly over q4 completes n.
    {
        const int h0 = 2 * wid, h1 = 2 * wid + 1;
        float pa[4];
        #pragma unroll
        for (int j = 0; j < 4; j++) pa[j] = 0.f;
        #pragma unroll
        for (int idx = 0; idx < 4; idx++) {
            const int n0 = q4 * 4 + idx, n1 = 16 + q4 * 4 + idx;
            float p00 = sP[n0][h0], p01 = sP[n0][h1];
            float p10 = sP[n1][h0], p11 = sP[n1][h1];
            pa[0] += p00 * vacc[0][0][idx] + p10 * vacc[1][0][idx];
            pa[1] += p00 * vacc[0][1][idx] + p10 * vacc[1][1][idx];
            pa[2] += p01 * vacc[0][2][idx] + p11 * vacc[1][2][idx];
            pa[3] += p01 * vacc[0][3][idx] + p11 * vacc[1][3][idx];
        }
        #pragma unroll
        for (int j = 0; j < 4; j++) {
            pa[j] += __shfl_xor(pa[j], 16);
            pa[j] += __shfl_xor(pa[j], 32);
        }
        if (q4 == 0) {
            #pragma unroll
            for (int j = 0; j < 4; j++) {
                int o = wid * 64 + j * 16 + l16;
                ag[(size_t)r * 256 + o] = pa[j] + bva[o];
            }
        }
    }
}

// ---------------- kernel C: z-proj, LN, FFN, residual, final LN (verified R1) ----
__global__ __launch_bounds__(256, 2)
void tail_kernel(const float* __restrict__ ag,
                 const float* __restrict__ bp,
                 const float* __restrict__ pre_w, const float* __restrict__ pre_b,
                 const float* __restrict__ b1, const float* __restrict__ b2,
                 const float* __restrict__ post_w, const float* __restrict__ post_b,
                 const unsigned short* __restrict__ wsb,
                 float* __restrict__ out) {
    const int tid  = threadIdx.x;
    const int lane = tid & 63;
    const int wid  = tid >> 6;
    const int q4   = lane >> 4;
    const int l16  = lane & 15;
    const int b    = blockIdx.x >> 8;
    const int m0   = (blockIdx.x & 255) * 16;

    const unsigned short* Wp_bf   = wsb + WPHI_OFF;
    const unsigned short* W1_bf   = wsb + W1_OFF;
    const unsigned short* W2_bf   = wsb + W2_OFF;
    const unsigned short* Wplo_bf = wsb + WPLO_OFF;

    __shared__ __align__(16) float Z[16][260];
    __shared__ __align__(16) unsigned short G[16][520];
    __shared__ __align__(16) unsigned short sQ[16][264];
    __shared__ __align__(16) float sAf[16][260];

    // load a
    #pragma unroll
    for (int rr = 0; rr < 4; rr++) {
        int m = wid * 4 + rr;
        *(float4*)&sAf[m][lane * 4] =
            *(const float4*)(ag + (size_t)(b * 4096 + m0 + m) * 256 + lane * 4);
    }
    __syncthreads();

    // z = sAf @ Wp^T + bp (hi/lo split for accuracy)
    {
        f32x4 acc[4];
        #pragma unroll
        for (int j = 0; j < 4; j++) acc[j] = 0.f;
        #pragma unroll
        for (int k = 0; k < 8; k++) {
            float4 va = *(const float4*)&sAf[l16][k * 32 + q4 * 8];
            float4 vb = *(const float4*)&sAf[l16][k * 32 + q4 * 8 + 4];
            float vs[8] = {va.x, va.y, va.z, va.w, vb.x, vb.y, vb.z, vb.w};
            bf16x8 ah, al;
            #pragma unroll
            for (int j = 0; j < 8; j++) {
                unsigned short hi = f2bf(vs[j]);
                ah[j] = (short)hi;
                al[j] = (short)f2bf(vs[j] - bf2f(hi));
            }
            #pragma unroll
            for (int j = 0; j < 4; j++) {
                int o = wid * 64 + j * 16 + l16;
                bf16x8 bh = *(const bf16x8*)(Wp_bf   + o * 256 + k * 32 + q4 * 8);
                bf16x8 bl = *(const bf16x8*)(Wplo_bf + o * 256 + k * 32 + q4 * 8);
                acc[j] = __builtin_amdgcn_mfma_f32_16x16x32_bf16(ah, bh, acc[j], 0, 0, 0);
                acc[j] = __builtin_amdgcn_mfma_f32_16x16x32_bf16(al, bh, acc[j], 0, 0, 0);
                acc[j] = __builtin_amdgcn_mfma_f32_16x16x32_bf16(ah, bl, acc[j], 0, 0, 0);
            }
        }
        #pragma unroll
        for (int j = 0; j < 4; j++) {
            int o = wid * 64 + j * 16 + l16;
            float bpv = bp[o];
            #pragma unroll
            for (int r = 0; r < 4; r++) Z[q4 * 4 + r][o] = acc[j][r] + bpv;
        }
    }
    __syncthreads();
    // pre-LN: normalize Z in place (residual base) + bf16 copy in sQ
    {
        const float4 w4 = *(const float4*)(pre_w + lane * 4);
        const float4 g4 = *(const float4*)(pre_b + lane * 4);
        #pragma unroll
        for (int rr = 0; rr < 4; rr++) {
            int m = wid * 4 + rr;
            float4 v = *(const float4*)&Z[m][lane * 4];
            float mu, inv; rowstats(v, mu, inv);
            float4 z;
            z.x = (v.x - mu) * inv * w4.x + g4.x;
            z.y = (v.y - mu) * inv * w4.y + g4.y;
            z.z = (v.z - mu) * inv * w4.z + g4.z;
            z.w = (v.w - mu) * inv * w4.w + g4.w;
            *(float4*)&Z[m][lane * 4] = z;
            ushort4 o;
            o.x = f2bf(z.x); o.y = f2bf(z.y); o.z = f2bf(z.z); o.w = f2bf(z.w);
            *(ushort4*)&sQ[m][lane * 4] = o;
        }
    }
    __syncthreads();
    // FFN1 + exact gelu -> G
    {
        f32x4 acc[8];
        #pragma unroll
        for (int j = 0; j < 8; j++) acc[j] = 0.f;
        #pragma unroll
        for (int k = 0; k < 8; k++) {
            bf16x8 af = *(const bf16x8*)&sQ[l16][k * 32 + q4 * 8];
            #pragma unroll
            for (int j = 0; j < 8; j++) {
                int f = wid * 128 + j * 16 + l16;
                bf16x8 bfv = *(const bf16x8*)(W1_bf + f * 256 + k * 32 + q4 * 8);
                acc[j] = __builtin_amdgcn_mfma_f32_16x16x32_bf16(af, bfv, acc[j], 0, 0, 0);
            }
        }
        #pragma unroll
        for (int j = 0; j < 8; j++) {
            int f = wid * 128 + j * 16 + l16;
            float b1v = b1[f];
            #pragma unroll
            for (int r = 0; r < 4; r++) {
                float vz = acc[j][r] + b1v;
                float g = 0.5f * vz * (1.f + erff(vz * 0.7071067811865475f));
                G[q4 * 4 + r][f] = f2bf(g);
            }
        }
    }
    __syncthreads();
    // FFN2 + residual -> Z
    {
        f32x4 acc[4];
        #pragma unroll
        for (int j = 0; j < 4; j++) acc[j] = 0.f;
        #pragma unroll
        for (int k = 0; k < 16; k++) {
            bf16x8 af = *(const bf16x8*)&G[l16][k * 32 + q4 * 8];
            #pragma unroll
            for (int j = 0; j < 4; j++) {
                int o = wid * 64 + j * 16 + l16;
                bf16x8 bfv = *(const bf16x8*)(W2_bf + o * 512 + k * 32 + q4 * 8);
                acc[j] = __builtin_amdgcn_mfma_f32_16x16x32_bf16(af, bfv, acc[j], 0, 0, 0);
            }
        }
        #pragma unroll
        for (int j = 0; j < 4; j++) {
            int o = wid * 64 + j * 16 + l16;
            float b2v = b2[o];
            #pragma unroll
            for (int r = 0; r < 4; r++) Z[q4 * 4 + r][o] += acc[j][r] + b2v;
        }
    }
    __syncthreads();
    // final LN -> out
    {
        const float4 w4 = *(const float4*)(post_w + lane * 4);
        const float4 g4 = *(const float4*)(post_b + lane * 4);
        #pragma unroll
        for (int rr = 0; rr < 4; rr++) {
            int m = wid * 4 + rr;
            float4 v = *(const float4*)&Z[m][lane * 4];
            float mu, inv; rowstats(v, mu, inv);
            float4 o;
            o.x = (v.x - mu) * inv * w4.x + g4.x;
            o.y = (v.y - mu) * inv * w4.y + g4.y;
            o.z = (v.z - mu) * inv * w4.z + g4.z;
            o.w = (v.w - mu) * inv * w4.w + g4.w;
            *(float4*)(out + (size_t)(b * 4096 + m0 + m) * 256 + lane * 4) = o;
        }
    }
}

extern "C" void kernel_launch(void* const* d_in, const int* in_sizes, int n_in,
                              void* d_out, int out_size, void* d_ws, size_t ws_size,
                              hipStream_t stream) {
    (void)in_sizes; (void)n_in; (void)out_size; (void)ws_size;
    const float* x      = (const float*)d_in[0];
    const float* y      = (const float*)d_in[1];
    const float* lnq_w  = (const float*)d_in[2];
    const float* lnq_b  = (const float*)d_in[3];
    const float* Wq     = (const float*)d_in[4];
    const float* bq     = (const float*)d_in[5];
    const float* lnk_w  = (const float*)d_in[6];
    // d_in[7] = lnk_b : softmax-invariant (dropped)
    const float* Wk     = (const float*)d_in[8];
    // d_in[9] = bk : softmax-invariant (dropped)
    const float* lnv_w  = (const float*)d_in[10];
    const float* lnv_b  = (const float*)d_in[11];
    const float* Wv     = (const float*)d_in[12];
    const float* bv     = (const float*)d_in[13];
    const float* Wp     = (const float*)d_in[14];
    const float* bp     = (const float*)d_in[15];
    const float* pre_w  = (const float*)d_in[16];
    const float* pre_b  = (const float*)d_in[17];
    const float* W1     = (const float*)d_in[18];
    const float* b1     = (const float*)d_in[19];
    const float* W2     = (const float*)d_in[20];
    const float* b2     = (const float*)d_in[21];
    const float* post_w = (const float*)d_in[22];
    const float* post_b = (const float*)d_in[23];
    unsigned short* wsb = (unsigned short*)d_ws;
    float* bva = (float*)(wsb + BVA_OFF);
    unsigned short* Tg = wsb + T_OFF;
    float* ag = (float*)(wsb + AG_OFF);

    prep_weights<<<2304, 256, 0, stream>>>(Wq, Wk, Wv, Wp, W1, W2, lnk_w, lnv_w, wsb);
    prep_bias<<<1, 256, 0, stream>>>(Wv, lnv_b, bv, bva);
    qt_kernel<<<512, 256, 0, stream>>>(x, lnq_w, lnq_b, bq, wsb, Tg);
    attn_kernel<<<8192, 256, 0, stream>>>(y, wsb, ag);
    tail_kernel<<<512, 256, 0, stream>>>(ag, bp, pre_w, pre_b, b1, b2, post_w, post_b,
                                         wsb, (float*)d_out);
}

// Round 5
// 592.407 us; speedup vs baseline: 2.8615x; 1.0038x over previous
//
#include <hip/hip_runtime.h>

#define LNEPS 1e-5f

typedef short bf16x8 __attribute__((ext_vector_type(8)));
typedef float f32x4 __attribute__((ext_vector_type(4)));

// ---------------- ws layout (ushort element offsets) ----------------
#define WQ_OFF    0
#define WKT_OFF   65536
#define WV_OFF    131072
#define WPHI_OFF  196608
#define W1_OFF    262144
#define W2_OFF    393216
#define WPLO_OFF  524288
#define BVA_OFF   589824
#define T_OFF     590336
#define AG_OFF    17367552

__device__ __forceinline__ unsigned short f2bf(float f) {
    union { float f; unsigned int u; } a; a.f = f;
    unsigned int u = a.u;
    unsigned int r = (u + 0x7fffu + ((u >> 16) & 1u)) >> 16;
    return (unsigned short)r;
}
__device__ __forceinline__ float bf2f(unsigned short h) {
    union { unsigned int u; float f; } a; a.u = ((unsigned int)h) << 16;
    return a.f;
}

__device__ __forceinline__ void rowstats(float4 v, float& mu, float& inv) {
    float s  = v.x + v.y + v.z + v.w;
    float ss = v.x * v.x + v.y * v.y + v.z * v.z + v.w * v.w;
    #pragma unroll
    for (int off = 32; off; off >>= 1) {
        s  += __shfl_xor(s, off);
        ss += __shfl_xor(ss, off);
    }
    mu  = s * (1.f / 256.f);
    float var = ss * (1.f / 256.f) - mu * mu;
    inv = rsqrtf(fmaxf(var, 0.f) + LNEPS);
}

// ---------------- prep: bf16 weights with LN-weight folds ----------------
__global__ void prep_weights(const float* __restrict__ Wq, const float* __restrict__ Wk,
                             const float* __restrict__ Wv, const float* __restrict__ Wp,
                             const float* __restrict__ W1, const float* __restrict__ W2,
                             const float* __restrict__ lnk_w, const float* __restrict__ lnv_w,
                             unsigned short* __restrict__ ws) {
    int i = blockIdx.x * 256 + threadIdx.x;
    if (i < 65536)       { ws[i] = f2bf(Wq[i]); }
    else if (i < 131072) { int l = i - 65536; int dp = l >> 8, o = l & 255;
                           ws[i] = f2bf(Wk[o * 256 + dp] * lnk_w[dp]); }
    else if (i < 196608) { int l = i - 131072; int dp = l & 255;
                           ws[i] = f2bf(Wv[l] * lnv_w[dp]); }
    else if (i < 262144) { ws[i] = f2bf(Wp[i - 196608]); }
    else if (i < 393216) { ws[i] = f2bf(W1[i - 262144]); }
    else if (i < 524288) { ws[i] = f2bf(W2[i - 393216]); }
    else if (i < 589824) { float w = Wp[i - 524288]; ws[i] = f2bf(w - bf2f(f2bf(w))); }
}

// bva[o] = bv[o] + sum_dp Wv[o][dp]*lnv_b[dp]   (exact since sum_n p = 1)
// 16 blocks x 256 threads; 16 threads per output o (each sums 16 dp), 16-lane-group reduce.
__global__ void prep_bias(const float* __restrict__ Wv, const float* __restrict__ lnv_b,
                          const float* __restrict__ bv, float* __restrict__ bva) {
    const int o   = blockIdx.x * 16 + (threadIdx.x >> 4);
    const int dp0 = (threadIdx.x & 15) * 16;
    float acc = 0.f;
    #pragma unroll
    for (int u = 0; u < 16; u += 4) {
        float4 w = *(const float4*)(Wv + o * 256 + dp0 + u);
        float4 g = *(const float4*)(lnv_b + dp0 + u);
        acc += w.x * g.x + w.y * g.y + w.z * g.z + w.w * g.w;
    }
    #pragma unroll
    for (int off = 8; off; off >>= 1) acc += __shfl_xor(acc, off);
    if ((threadIdx.x & 15) == 0) bva[o] = acc + bv[o];
}

// ---------------- kernel A: LN(x) -> q' -> T = q' @ WkT_f (MFMA) ----------------
__global__ __launch_bounds__(256, 2)
void qt_kernel(const float* __restrict__ x,
               const float* __restrict__ lnq_w, const float* __restrict__ lnq_b,
               const float* __restrict__ bq,
               const unsigned short* __restrict__ wsb, unsigned short* __restrict__ Tg) {
    const int tid  = threadIdx.x;
    const int lane = tid & 63;
    const int wid  = tid >> 6;
    const int q4   = lane >> 4;
    const int l16  = lane & 15;
    const int b    = blockIdx.x >> 8;
    const int m0   = (blockIdx.x & 255) * 16;
    const float scale = 0.17677669529663687f; // 1/sqrt(32)

    const unsigned short* Wq_bf  = wsb + WQ_OFF;
    const unsigned short* WkT_bf = wsb + WKT_OFF;

    __shared__ __align__(16) unsigned short lnX[16][264];
    __shared__ __align__(16) unsigned short sQ[16][264];

    // P1: layernorm(x) -> lnX (bf16, lnq affine)
    {
        const float4 w4 = *(const float4*)(lnq_w + lane * 4);
        const float4 g4 = *(const float4*)(lnq_b + lane * 4);
        float4 xv[4];
        #pragma unroll
        for (int rr = 0; rr < 4; rr++) {
            int m = wid * 4 + rr;
            xv[rr] = *(const float4*)(x + (size_t)(b * 4096 + m0 + m) * 256 + lane * 4);
        }
        #pragma unroll
        for (int rr = 0; rr < 4; rr++) {
            int m = wid * 4 + rr;
            float mu, inv; rowstats(xv[rr], mu, inv);
            float4 v = xv[rr];
            ushort4 o;
            o.x = f2bf((v.x - mu) * inv * w4.x + g4.x);
            o.y = f2bf((v.y - mu) * inv * w4.y + g4.y);
            o.z = f2bf((v.z - mu) * inv * w4.z + g4.z);
            o.w = f2bf((v.w - mu) * inv * w4.w + g4.w);
            *(ushort4*)&lnX[m][lane * 4] = o;
        }
    }
    __syncthreads();

    // P2: q' = (lnX @ Wq^T + bq) * scale -> sQ (bf16)
    {
        f32x4 acc[4];
        #pragma unroll
        for (int j = 0; j < 4; j++) acc[j] = 0.f;
        #pragma unroll
        for (int k = 0; k < 8; k++) {
            bf16x8 af = *(const bf16x8*)&lnX[l16][k * 32 + q4 * 8];
            #pragma unroll
            for (int j = 0; j < 4; j++) {
                int o = wid * 64 + j * 16 + l16;
                bf16x8 bfv = *(const bf16x8*)(Wq_bf + o * 256 + k * 32 + q4 * 8);
                acc[j] = __builtin_amdgcn_mfma_f32_16x16x32_bf16(af, bfv, acc[j], 0, 0, 0);
            }
        }
        #pragma unroll
        for (int j = 0; j < 4; j++) {
            int o = wid * 64 + j * 16 + l16;
            float bqv = bq[o];
            #pragma unroll
            for (int r = 0; r < 4; r++) {
                sQ[q4 * 4 + r][o] = f2bf((acc[j][r] + bqv) * scale);
            }
        }
    }
    __syncthreads();

    // T[m][h][dp] = sum_d q'[m][h*32+d] * WkT_f[dp][h*32+d]
    {
        const size_t rowbase = (size_t)(b * 4096 + m0) * 2048;
        #pragma unroll
        for (int h = 0; h < 8; h++) {
            bf16x8 af = *(const bf16x8*)&sQ[l16][h * 32 + q4 * 8];
            #pragma unroll
            for (int t = 0; t < 4; t++) {
                const int dp0 = (wid * 4 + t) * 16;
                bf16x8 bfv = *(const bf16x8*)(WkT_bf + (size_t)(dp0 + l16) * 256 + h * 32 + q4 * 8);
                f32x4 acc = {0.f, 0.f, 0.f, 0.f};
                acc = __builtin_amdgcn_mfma_f32_16x16x32_bf16(af, bfv, acc, 0, 0, 0);
                #pragma unroll
                for (int r = 0; r < 4; r++) {
                    int ml = q4 * 4 + r;
                    Tg[rowbase + (size_t)ml * 2048 + h * 256 + dp0 + l16] = f2bf(acc[r]);
                }
            }
        }
    }
}

// ---------------- kernel B: per-m-row attention (MFMA logits + MFMA V) --------
// grid = 8192 blocks (one per (b,m)); 4 waves; ~26.5 KB LDS.
__global__ __launch_bounds__(256, 4)
void attn_kernel(const float* __restrict__ y,
                 const unsigned short* __restrict__ wsb,
                 float* __restrict__ ag) {
    const int tid  = threadIdx.x;
    const int lane = tid & 63;
    const int wid  = tid >> 6;
    const int q4   = lane >> 4;
    const int l16  = lane & 15;
    const int r    = blockIdx.x;                 // b*4096 + m

    const unsigned short* Wv_bf = wsb + WV_OFF;
    const unsigned short* Tg    = wsb + T_OFF;
    const float*          bva   = (const float*)(wsb + BVA_OFF);

    __shared__ __align__(16) unsigned short Y[32][264];    // normalized y (no affine)
    __shared__ __align__(16) unsigned short Tbf[16][264];  // T row bf16, rows 8..15 = 0
    __shared__ __align__(16) float sP[32][9];              // logits -> probs

    // load T row (4 KB bf16) and zero the pad rows
    {
        bf16x8 t8 = *(const bf16x8*)(Tg + (size_t)r * 2048 + tid * 8);
        *(bf16x8*)&Tbf[tid >> 5][(tid & 31) * 8] = t8;
        bf16x8 z8;
        #pragma unroll
        for (int j = 0; j < 8; j++) z8[j] = 0;
        *(bf16x8*)&Tbf[8 + (tid >> 5)][(tid & 31) * 8] = z8;
    }
    // load y (32 KB) + LN -> Y (each wave does 8 rows)
    {
        const float* yb = y + (size_t)r * 8192;
        float4 vv[8];
        #pragma unroll
        for (int u = 0; u < 8; u++) {
            int n = wid * 8 + u;
            vv[u] = *(const float4*)(yb + n * 256 + lane * 4);
        }
        #pragma unroll
        for (int u = 0; u < 8; u++) {
            int n = wid * 8 + u;
            float mu, inv; rowstats(vv[u], mu, inv);
            float4 v = vv[u];
            ushort4 o;
            o.x = f2bf((v.x - mu) * inv);
            o.y = f2bf((v.y - mu) * inv);
            o.z = f2bf((v.z - mu) * inv);
            o.w = f2bf((v.w - mu) * inv);
            *(ushort4*)&Y[n][lane * 4] = o;
        }
    }
    __syncthreads();

    // V[n][o] = Y[n] . Wv_f[o]  (MFMA; acc stays in registers)
    // wave w owns o = w*64 .. w*64+63 (4 o-tiles), both n-tiles.
    f32x4 vacc[2][4];
    #pragma unroll
    for (int nt = 0; nt < 2; nt++)
        #pragma unroll
        for (int j = 0; j < 4; j++) vacc[nt][j] = 0.f;
    #pragma unroll
    for (int k = 0; k < 8; k++) {
        bf16x8 a0 = *(const bf16x8*)&Y[l16][k * 32 + q4 * 8];
        bf16x8 a1 = *(const bf16x8*)&Y[16 + l16][k * 32 + q4 * 8];
        #pragma unroll
        for (int j = 0; j < 4; j++) {
            int o = wid * 64 + j * 16 + l16;
            bf16x8 bv8 = *(const bf16x8*)(Wv_bf + (size_t)o * 256 + k * 32 + q4 * 8);
            vacc[0][j] = __builtin_amdgcn_mfma_f32_16x16x32_bf16(a0, bv8, vacc[0][j], 0, 0, 0);
            vacc[1][j] = __builtin_amdgcn_mfma_f32_16x16x32_bf16(a1, bv8, vacc[1][j], 0, 0, 0);
        }
    }

    // logits[n][h] = Y[n] . Tbf[h]  (MFMA; waves 0,1 only, one n-tile each)
    if (wid < 2) {
        f32x4 lacc = {0.f, 0.f, 0.f, 0.f};
        #pragma unroll
        for (int k = 0; k < 8; k++) {
            bf16x8 af = *(const bf16x8*)&Y[wid * 16 + l16][k * 32 + q4 * 8];
            bf16x8 bf = *(const bf16x8*)&Tbf[l16][k * 32 + q4 * 8];
            lacc = __builtin_amdgcn_mfma_f32_16x16x32_bf16(af, bf, lacc, 0, 0, 0);
        }
        if (l16 < 8) {
            #pragma unroll
            for (int rr = 0; rr < 4; rr++)
                sP[wid * 16 + q4 * 4 + rr][l16] = lacc[rr];
        }
    }
    __syncthreads();

    // softmax over n (thread -> (h = tid>>5, n = tid&31))
    {
        const int h = tid >> 5, n = tid & 31;
        float v = sP[n][h];
        float mx = v;
        #pragma unroll
        for (int off = 16; off; off >>= 1) mx = fmaxf(mx, __shfl_xor(mx, off));
        float e = __expf(v - mx);
        float s = e;
        #pragma unroll
        for (int off = 16; off; off >>= 1) s += __shfl_xor(s, off);
        sP[n][h] = e / s;
    }
    __syncthreads();

    // a[o] = sum_n P[n][h(o)] * V[n][o] + bva[o]
    // lane holds V rows n in {q4*4+idx, 16+q4*4+idx}; butterfly over q4 completes n.
    {
        const int h0 = 2 * wid, h1 = 2 * wid + 1;
        float pa[4];
        #pragma unroll
        for (int j = 0; j < 4; j++) pa[j] = 0.f;
        #pragma unroll
        for (int idx = 0; idx < 4; idx++) {
            const int n0 = q4 * 4 + idx, n1 = 16 + q4 * 4 + idx;
            float p00 = sP[n0][h0], p01 = sP[n0][h1];
            float p10 = sP[n1][h0], p11 = sP[n1][h1];
            pa[0] += p00 * vacc[0][0][idx] + p10 * vacc[1][0][idx];
            pa[1] += p00 * vacc[0][1][idx] + p10 * vacc[1][1][idx];
            pa[2] += p01 * vacc[0][2][idx] + p11 * vacc[1][2][idx];
            pa[3] += p01 * vacc[0][3][idx] + p11 * vacc[1][3][idx];
        }
        #pragma unroll
        for (int j = 0; j < 4; j++) {
            pa[j] += __shfl_xor(pa[j], 16);
            pa[j] += __shfl_xor(pa[j], 32);
        }
        if (q4 == 0) {
            #pragma unroll
            for (int j = 0; j < 4; j++) {
                int o = wid * 64 + j * 16 + l16;
                ag[(size_t)r * 256 + o] = pa[j] + bva[o];
            }
        }
    }
}

// ---------------- kernel C: z-proj, LN, FFN, residual, final LN (verified R1) ----
__global__ __launch_bounds__(256, 2)
void tail_kernel(const float* __restrict__ ag,
                 const float* __restrict__ bp,
                 const float* __restrict__ pre_w, const float* __restrict__ pre_b,
                 const float* __restrict__ b1, const float* __restrict__ b2,
                 const float* __restrict__ post_w, const float* __restrict__ post_b,
                 const unsigned short* __restrict__ wsb,
                 float* __restrict__ out) {
    const int tid  = threadIdx.x;
    const int lane = tid & 63;
    const int wid  = tid >> 6;
    const int q4   = lane >> 4;
    const int l16  = lane & 15;
    const int b    = blockIdx.x >> 8;
    const int m0   = (blockIdx.x & 255) * 16;

    const unsigned short* Wp_bf   = wsb + WPHI_OFF;
    const unsigned short* W1_bf   = wsb + W1_OFF;
    const unsigned short* W2_bf   = wsb + W2_OFF;
    const unsigned short* Wplo_bf = wsb + WPLO_OFF;

    __shared__ __align__(16) float Z[16][260];
    __shared__ __align__(16) unsigned short G[16][520];
    __shared__ __align__(16) unsigned short sQ[16][264];
    __shared__ __align__(16) float sAf[16][260];

    // load a
    #pragma unroll
    for (int rr = 0; rr < 4; rr++) {
        int m = wid * 4 + rr;
        *(float4*)&sAf[m][lane * 4] =
            *(const float4*)(ag + (size_t)(b * 4096 + m0 + m) * 256 + lane * 4);
    }
    __syncthreads();

    // z = sAf @ Wp^T + bp (hi/lo split for accuracy)
    {
        f32x4 acc[4];
        #pragma unroll
        for (int j = 0; j < 4; j++) acc[j] = 0.f;
        #pragma unroll
        for (int k = 0; k < 8; k++) {
            float4 va = *(const float4*)&sAf[l16][k * 32 + q4 * 8];
            float4 vb = *(const float4*)&sAf[l16][k * 32 + q4 * 8 + 4];
            float vs[8] = {va.x, va.y, va.z, va.w, vb.x, vb.y, vb.z, vb.w};
            bf16x8 ah, al;
            #pragma unroll
            for (int j = 0; j < 8; j++) {
                unsigned short hi = f2bf(vs[j]);
                ah[j] = (short)hi;
                al[j] = (short)f2bf(vs[j] - bf2f(hi));
            }
            #pragma unroll
            for (int j = 0; j < 4; j++) {
                int o = wid * 64 + j * 16 + l16;
                bf16x8 bh = *(const bf16x8*)(Wp_bf   + o * 256 + k * 32 + q4 * 8);
                bf16x8 bl = *(const bf16x8*)(Wplo_bf + o * 256 + k * 32 + q4 * 8);
                acc[j] = __builtin_amdgcn_mfma_f32_16x16x32_bf16(ah, bh, acc[j], 0, 0, 0);
                acc[j] = __builtin_amdgcn_mfma_f32_16x16x32_bf16(al, bh, acc[j], 0, 0, 0);
                acc[j] = __builtin_amdgcn_mfma_f32_16x16x32_bf16(ah, bl, acc[j], 0, 0, 0);
            }
        }
        #pragma unroll
        for (int j = 0; j < 4; j++) {
            int o = wid * 64 + j * 16 + l16;
            float bpv = bp[o];
            #pragma unroll
            for (int r = 0; r < 4; r++) Z[q4 * 4 + r][o] = acc[j][r] + bpv;
        }
    }
    __syncthreads();
    // pre-LN: normalize Z in place (residual base) + bf16 copy in sQ
    {
        const float4 w4 = *(const float4*)(pre_w + lane * 4);
        const float4 g4 = *(const float4*)(pre_b + lane * 4);
        #pragma unroll
        for (int rr = 0; rr < 4; rr++) {
            int m = wid * 4 + rr;
            float4 v = *(const float4*)&Z[m][lane * 4];
            float mu, inv; rowstats(v, mu, inv);
            float4 z;
            z.x = (v.x - mu) * inv * w4.x + g4.x;
            z.y = (v.y - mu) * inv * w4.y + g4.y;
            z.z = (v.z - mu) * inv * w4.z + g4.z;
            z.w = (v.w - mu) * inv * w4.w + g4.w;
            *(float4*)&Z[m][lane * 4] = z;
            ushort4 o;
            o.x = f2bf(z.x); o.y = f2bf(z.y); o.z = f2bf(z.z); o.w = f2bf(z.w);
            *(ushort4*)&sQ[m][lane * 4] = o;
        }
    }
    __syncthreads();
    // FFN1 + exact gelu -> G
    {
        f32x4 acc[8];
        #pragma unroll
        for (int j = 0; j < 8; j++) acc[j] = 0.f;
        #pragma unroll
        for (int k = 0; k < 8; k++) {
            bf16x8 af = *(const bf16x8*)&sQ[l16][k * 32 + q4 * 8];
            #pragma unroll
            for (int j = 0; j < 8; j++) {
                int f = wid * 128 + j * 16 + l16;
                bf16x8 bfv = *(const bf16x8*)(W1_bf + f * 256 + k * 32 + q4 * 8);
                acc[j] = __builtin_amdgcn_mfma_f32_16x16x32_bf16(af, bfv, acc[j], 0, 0, 0);
            }
        }
        #pragma unroll
        for (int j = 0; j < 8; j++) {
            int f = wid * 128 + j * 16 + l16;
            float b1v = b1[f];
            #pragma unroll
            for (int r = 0; r < 4; r++) {
                float vz = acc[j][r] + b1v;
                float g = 0.5f * vz * (1.f + erff(vz * 0.7071067811865475f));
                G[q4 * 4 + r][f] = f2bf(g);
            }
        }
    }
    __syncthreads();
    // FFN2 + residual -> Z
    {
        f32x4 acc[4];
        #pragma unroll
        for (int j = 0; j < 4; j++) acc[j] = 0.f;
        #pragma unroll
        for (int k = 0; k < 16; k++) {
            bf16x8 af = *(const bf16x8*)&G[l16][k * 32 + q4 * 8];
            #pragma unroll
            for (int j = 0; j < 4; j++) {
                int o = wid * 64 + j * 16 + l16;
                bf16x8 bfv = *(const bf16x8*)(W2_bf + o * 512 + k * 32 + q4 * 8);
                acc[j] = __builtin_amdgcn_mfma_f32_16x16x32_bf16(af, bfv, acc[j], 0, 0, 0);
            }
        }
        #pragma unroll
        for (int j = 0; j < 4; j++) {
            int o = wid * 64 + j * 16 + l16;
            float b2v = b2[o];
            #pragma unroll
            for (int r = 0; r < 4; r++) Z[q4 * 4 + r][o] += acc[j][r] + b2v;
        }
    }
    __syncthreads();
    // final LN -> out
    {
        const float4 w4 = *(const float4*)(post_w + lane * 4);
        const float4 g4 = *(const float4*)(post_b + lane * 4);
        #pragma unroll
        for (int rr = 0; rr < 4; rr++) {
            int m = wid * 4 + rr;
            float4 v = *(const float4*)&Z[m][lane * 4];
            float mu, inv; rowstats(v, mu, inv);
            float4 o;
            o.x = (v.x - mu) * inv * w4.x + g4.x;
            o.y = (v.y - mu) * inv * w4.y + g4.y;
            o.z = (v.z - mu) * inv * w4.z + g4.z;
            o.w = (v.w - mu) * inv * w4.w + g4.w;
            *(float4*)(out + (size_t)(b * 4096 + m0 + m) * 256 + lane * 4) = o;
        }
    }
}

extern "C" void kernel_launch(void* const* d_in, const int* in_sizes, int n_in,
                              void* d_out, int out_size, void* d_ws, size_t ws_size,
                              hipStream_t stream) {
    (void)in_sizes; (void)n_in; (void)out_size; (void)ws_size;
    const float* x      = (const float*)d_in[0];
    const float* y      = (const float*)d_in[1];
    const float* lnq_w  = (const float*)d_in[2];
    const float* lnq_b  = (const float*)d_in[3];
    const float* Wq     = (const float*)d_in[4];
    const float* bq     = (const float*)d_in[5];
    const float* lnk_w  = (const float*)d_in[6];
    // d_in[7] = lnk_b : softmax-invariant (dropped)
    const float* Wk     = (const float*)d_in[8];
    // d_in[9] = bk : softmax-invariant (dropped)
    const float* lnv_w  = (const float*)d_in[10];
    const float* lnv_b  = (const float*)d_in[11];
    const float* Wv     = (const float*)d_in[12];
    const float* bv     = (const float*)d_in[13];
    const float* Wp     = (const float*)d_in[14];
    const float* bp     = (const float*)d_in[15];
    const float* pre_w  = (const float*)d_in[16];
    const float* pre_b  = (const float*)d_in[17];
    const float* W1     = (const float*)d_in[18];
    const float* b1     = (const float*)d_in[19];
    const float* W2     = (const float*)d_in[20];
    const float* b2     = (const float*)d_in[21];
    const float* post_w = (const float*)d_in[22];
    const float* post_b = (const float*)d_in[23];
    unsigned short* wsb = (unsigned short*)d_ws;
    float* bva = (float*)(wsb + BVA_OFF);
    unsigned short* Tg = wsb + T_OFF;
    float* ag = (float*)(wsb + AG_OFF);

    prep_weights<<<2304, 256, 0, stream>>>(Wq, Wk, Wv, Wp, W1, W2, lnk_w, lnv_w, wsb);
    prep_bias<<<16, 256, 0, stream>>>(Wv, lnv_b, bv, bva);
    qt_kernel<<<512, 256, 0, stream>>>(x, lnq_w, lnq_b, bq, wsb, Tg);
    attn_kernel<<<8192, 256, 0, stream>>>(y, wsb, ag);
    tail_kernel<<<512, 256, 0, stream>>>(ag, bp, pre_w, pre_b, b1, b2, post_w, post_b,
                                         wsb, (float*)d_out);
}

// Round 7
// 486.812 us; speedup vs baseline: 3.4822x; 1.2169x over previous
//
#include <hip/hip_runtime.h>

#define LNEPS 1e-5f

typedef short bf16x8 __attribute__((ext_vector_type(8)));
typedef float f32x4 __attribute__((ext_vector_type(4)));

// ---------------- ws layout (ushort element offsets) ----------------
// All weight regions hold FRAGMENT-SWIZZLED bf16:
//   SW[((otile*NK + k)*64 + lane)*8 + i] = W[otile*16 + (lane&15)][k*32 + (lane>>4)*8 + i]
// so a wave's MFMA B-fragment load is one contiguous 1KB read.
#define WQ_OFF    0
#define WKT_OFF   65536
#define WV_OFF    131072
#define WPHI_OFF  196608
#define W1_OFF    262144
#define W2_OFF    393216
#define WPLO_OFF  524288
#define BVA_OFF   589824
#define T_OFF     590336
#define AG_OFF    17367552

__device__ __forceinline__ unsigned short f2bf(float f) {
    union { float f; unsigned int u; } a; a.f = f;
    unsigned int u = a.u;
    unsigned int r = (u + 0x7fffu + ((u >> 16) & 1u)) >> 16;
    return (unsigned short)r;
}
__device__ __forceinline__ float bf2f(unsigned short h) {
    union { unsigned int u; float f; } a; a.u = ((unsigned int)h) << 16;
    return a.f;
}

__device__ __forceinline__ void rowstats(float4 v, float& mu, float& inv) {
    float s  = v.x + v.y + v.z + v.w;
    float ss = v.x * v.x + v.y * v.y + v.z * v.z + v.w * v.w;
    #pragma unroll
    for (int off = 32; off; off >>= 1) {
        s  += __shfl_xor(s, off);
        ss += __shfl_xor(ss, off);
    }
    mu  = s * (1.f / 256.f);
    float var = ss * (1.f / 256.f) - mu * mu;
    inv = rsqrtf(fmaxf(var, 0.f) + LNEPS);
}

// ---------------- prep: bf16 weights, fragment-swizzled, LN folds ----------------
__global__ void prep_weights(const float* __restrict__ Wq, const float* __restrict__ Wk,
                             const float* __restrict__ Wv, const float* __restrict__ Wp,
                             const float* __restrict__ W1, const float* __restrict__ W2,
                             const float* __restrict__ lnk_w, const float* __restrict__ lnv_w,
                             unsigned short* __restrict__ ws) {
    int i = blockIdx.x * 256 + threadIdx.x;
    if (i < 131072) {
        int l, isK = (i >= 65536);
        l = isK ? i - 65536 : i;
        int e = l & 7, lane = (l >> 3) & 63, t = l >> 9;
        int k = t & 7, ot = t >> 3;
        int row = ot * 16 + (lane & 15);
        int col = k * 32 + (lane >> 4) * 8 + e;
        float v;
        if (!isK) v = Wq[row * 256 + col];                       // Wq[o][dp]
        else      v = Wk[col * 256 + row] * lnk_w[row];          // WkT[dp][c]
        ws[i] = f2bf(v);
    } else if (i < 262144) {
        int l = i - 131072, isP = (l >= 65536);
        if (isP) l -= 65536;
        int e = l & 7, lane = (l >> 3) & 63, t = l >> 9;
        int k = t & 7, ot = t >> 3;
        int row = ot * 16 + (lane & 15);
        int col = k * 32 + (lane >> 4) * 8 + e;
        float v;
        if (!isP) v = Wv[row * 256 + col] * lnv_w[col];          // Wv_f[o][dp]
        else      v = Wp[row * 256 + col];                       // Wp hi
        ws[i] = f2bf(v);
    } else if (i < 393216) {
        int l = i - 262144;
        int e = l & 7, lane = (l >> 3) & 63, t = l >> 9;
        int k = t & 7, ot = t >> 3;                              // ot 0..31
        int row = ot * 16 + (lane & 15);
        int col = k * 32 + (lane >> 4) * 8 + e;
        ws[i] = f2bf(W1[row * 256 + col]);
    } else if (i < 524288) {
        int l = i - 393216;
        int e = l & 7, lane = (l >> 3) & 63, t = l >> 9;
        int k = t & 15, ot = t >> 4;                             // NK=16
        int row = ot * 16 + (lane & 15);
        int col = k * 32 + (lane >> 4) * 8 + e;
        ws[i] = f2bf(W2[row * 512 + col]);
    } else if (i < 589824) {
        int l = i - 524288;
        int e = l & 7, lane = (l >> 3) & 63, t = l >> 9;
        int k = t & 7, ot = t >> 3;
        int row = ot * 16 + (lane & 15);
        int col = k * 32 + (lane >> 4) * 8 + e;
        float w = Wp[row * 256 + col];
        ws[i] = f2bf(w - bf2f(f2bf(w)));                         // Wp lo
    }
}

// bva[o] = bv[o] + sum_dp Wv[o][dp]*lnv_b[dp]   (exact since sum_n p = 1)
__global__ void prep_bias(const float* __restrict__ Wv, const float* __restrict__ lnv_b,
                          const float* __restrict__ bv, float* __restrict__ bva) {
    const int o   = blockIdx.x * 16 + (threadIdx.x >> 4);
    const int dp0 = (threadIdx.x & 15) * 16;
    float acc = 0.f;
    #pragma unroll
    for (int u = 0; u < 16; u += 4) {
        float4 w = *(const float4*)(Wv + o * 256 + dp0 + u);
        float4 g = *(const float4*)(lnv_b + dp0 + u);
        acc += w.x * g.x + w.y * g.y + w.z * g.z + w.w * g.w;
    }
    #pragma unroll
    for (int off = 8; off; off >>= 1) acc += __shfl_xor(acc, off);
    if ((threadIdx.x & 15) == 0) bva[o] = acc + bv[o];
}

// ---------------- kernel A: LN(x) -> q' -> T = q' @ WkT_f (MFMA) ----------------
__global__ __launch_bounds__(256, 2)
void qt_kernel(const float* __restrict__ x,
               const float* __restrict__ lnq_w, const float* __restrict__ lnq_b,
               const float* __restrict__ bq,
               const unsigned short* __restrict__ wsb, unsigned short* __restrict__ Tg) {
    const int tid  = threadIdx.x;
    const int lane = tid & 63;
    const int wid  = tid >> 6;
    const int q4   = lane >> 4;
    const int l16  = lane & 15;
    const int b    = blockIdx.x >> 8;
    const int m0   = (blockIdx.x & 255) * 16;
    const float scale = 0.17677669529663687f; // 1/sqrt(32)

    const unsigned short* Wq_bf  = wsb + WQ_OFF;
    const unsigned short* WkT_bf = wsb + WKT_OFF;

    __shared__ __align__(16) unsigned short lnX[16][264];
    __shared__ __align__(16) unsigned short sQ[16][264];

    // P1: layernorm(x) -> lnX (bf16, lnq affine)
    {
        const float4 w4 = *(const float4*)(lnq_w + lane * 4);
        const float4 g4 = *(const float4*)(lnq_b + lane * 4);
        float4 xv[4];
        #pragma unroll
        for (int rr = 0; rr < 4; rr++) {
            int m = wid * 4 + rr;
            xv[rr] = *(const float4*)(x + (size_t)(b * 4096 + m0 + m) * 256 + lane * 4);
        }
        #pragma unroll
        for (int rr = 0; rr < 4; rr++) {
            int m = wid * 4 + rr;
            float mu, inv; rowstats(xv[rr], mu, inv);
            float4 v = xv[rr];
            ushort4 o;
            o.x = f2bf((v.x - mu) * inv * w4.x + g4.x);
            o.y = f2bf((v.y - mu) * inv * w4.y + g4.y);
            o.z = f2bf((v.z - mu) * inv * w4.z + g4.z);
            o.w = f2bf((v.w - mu) * inv * w4.w + g4.w);
            *(ushort4*)&lnX[m][lane * 4] = o;
        }
    }
    __syncthreads();

    // P2: q' = (lnX @ Wq^T + bq) * scale -> sQ (bf16)
    {
        f32x4 acc[4];
        #pragma unroll
        for (int j = 0; j < 4; j++) acc[j] = 0.f;
        #pragma unroll
        for (int k = 0; k < 8; k++) {
            bf16x8 af = *(const bf16x8*)&lnX[l16][k * 32 + q4 * 8];
            #pragma unroll
            for (int j = 0; j < 4; j++) {
                bf16x8 bfv = *(const bf16x8*)(Wq_bf + ((((wid * 4 + j) * 8 + k) * 64 + lane) << 3));
                acc[j] = __builtin_amdgcn_mfma_f32_16x16x32_bf16(af, bfv, acc[j], 0, 0, 0);
            }
        }
        #pragma unroll
        for (int j = 0; j < 4; j++) {
            int o = wid * 64 + j * 16 + l16;
            float bqv = bq[o];
            #pragma unroll
            for (int r = 0; r < 4; r++) {
                sQ[q4 * 4 + r][o] = f2bf((acc[j][r] + bqv) * scale);
            }
        }
    }
    __syncthreads();

    // T[m][h][dp] = sum_d q'[m][h*32+d] * WkT_f[dp][h*32+d]
    {
        const size_t rowbase = (size_t)(b * 4096 + m0) * 2048;
        #pragma unroll
        for (int h = 0; h < 8; h++) {
            bf16x8 af = *(const bf16x8*)&sQ[l16][h * 32 + q4 * 8];
            #pragma unroll
            for (int t = 0; t < 4; t++) {
                const int dp0 = (wid * 4 + t) * 16;
                bf16x8 bfv = *(const bf16x8*)(WkT_bf + ((((wid * 4 + t) * 8 + h) * 64 + lane) << 3));
                f32x4 acc = {0.f, 0.f, 0.f, 0.f};
                acc = __builtin_amdgcn_mfma_f32_16x16x32_bf16(af, bfv, acc, 0, 0, 0);
                #pragma unroll
                for (int r = 0; r < 4; r++) {
                    int ml = q4 * 4 + r;
                    Tg[rowbase + (size_t)ml * 2048 + h * 256 + dp0 + l16] = f2bf(acc[r]);
                }
            }
        }
    }
}

// ---------------- kernel B: per-m-row attention (MFMA logits + MFMA V) --------
// grid = 8192 blocks (one per (b,m)); 4 waves; ~26.5 KB LDS.
__global__ __launch_bounds__(256, 4)
void attn_kernel(const float* __restrict__ y,
                 const unsigned short* __restrict__ wsb,
                 float* __restrict__ ag) {
    const int tid  = threadIdx.x;
    const int lane = tid & 63;
    const int wid  = tid >> 6;
    const int q4   = lane >> 4;
    const int l16  = lane & 15;
    const int r    = blockIdx.x;                 // b*4096 + m

    const unsigned short* Wv_bf = wsb + WV_OFF;
    const unsigned short* Tg    = wsb + T_OFF;
    const float*          bva   = (const float*)(wsb + BVA_OFF);

    __shared__ __align__(16) unsigned short Y[32][264];    // normalized y (no affine)
    __shared__ __align__(16) unsigned short Tbf[16][264];  // T row bf16, rows 8..15 = 0
    __shared__ __align__(16) float sP[32][9];              // logits -> probs

    // load T row (4 KB bf16) and zero the pad rows
    {
        bf16x8 t8 = *(const bf16x8*)(Tg + (size_t)r * 2048 + tid * 8);
        *(bf16x8*)&Tbf[tid >> 5][(tid & 31) * 8] = t8;
        bf16x8 z8;
        #pragma unroll
        for (int j = 0; j < 8; j++) z8[j] = 0;
        *(bf16x8*)&Tbf[8 + (tid >> 5)][(tid & 31) * 8] = z8;
    }
    // load y (32 KB) + LN -> Y (each wave does 8 rows)
    {
        const float* yb = y + (size_t)r * 8192;
        float4 vv[8];
        #pragma unroll
        for (int u = 0; u < 8; u++) {
            int n = wid * 8 + u;
            vv[u] = *(const float4*)(yb + n * 256 + lane * 4);
        }
        #pragma unroll
        for (int u = 0; u < 8; u++) {
            int n = wid * 8 + u;
            float mu, inv; rowstats(vv[u], mu, inv);
            float4 v = vv[u];
            ushort4 o;
            o.x = f2bf((v.x - mu) * inv);
            o.y = f2bf((v.y - mu) * inv);
            o.z = f2bf((v.z - mu) * inv);
            o.w = f2bf((v.w - mu) * inv);
            *(ushort4*)&Y[n][lane * 4] = o;
        }
    }
    __syncthreads();

    // V[n][o] = Y[n] . Wv_f[o]  (MFMA; acc stays in registers)
    f32x4 vacc[2][4];
    #pragma unroll
    for (int nt = 0; nt < 2; nt++)
        #pragma unroll
        for (int j = 0; j < 4; j++) vacc[nt][j] = 0.f;
    #pragma unroll
    for (int k = 0; k < 8; k++) {
        bf16x8 a0 = *(const bf16x8*)&Y[l16][k * 32 + q4 * 8];
        bf16x8 a1 = *(const bf16x8*)&Y[16 + l16][k * 32 + q4 * 8];
        #pragma unroll
        for (int j = 0; j < 4; j++) {
            bf16x8 bv8 = *(const bf16x8*)(Wv_bf + ((((wid * 4 + j) * 8 + k) * 64 + lane) << 3));
            vacc[0][j] = __builtin_amdgcn_mfma_f32_16x16x32_bf16(a0, bv8, vacc[0][j], 0, 0, 0);
            vacc[1][j] = __builtin_amdgcn_mfma_f32_16x16x32_bf16(a1, bv8, vacc[1][j], 0, 0, 0);
        }
    }

    // logits[n][h] = Y[n] . Tbf[h]  (MFMA; waves 0,1 only, one n-tile each)
    if (wid < 2) {
        f32x4 lacc = {0.f, 0.f, 0.f, 0.f};
        #pragma unroll
        for (int k = 0; k < 8; k++) {
            bf16x8 af = *(const bf16x8*)&Y[wid * 16 + l16][k * 32 + q4 * 8];
            bf16x8 bf = *(const bf16x8*)&Tbf[l16][k * 32 + q4 * 8];
            lacc = __builtin_amdgcn_mfma_f32_16x16x32_bf16(af, bf, lacc, 0, 0, 0);
        }
        if (l16 < 8) {
            #pragma unroll
            for (int rr = 0; rr < 4; rr++)
                sP[wid * 16 + q4 * 4 + rr][l16] = lacc[rr];
        }
    }
    __syncthreads();

    // softmax over n (thread -> (h = tid>>5, n = tid&31))
    {
        const int h = tid >> 5, n = tid & 31;
        float v = sP[n][h];
        float mx = v;
        #pragma unroll
        for (int off = 16; off; off >>= 1) mx = fmaxf(mx, __shfl_xor(mx, off));
        float e = __expf(v - mx);
        float s = e;
        #pragma unroll
        for (int off = 16; off; off >>= 1) s += __shfl_xor(s, off);
        sP[n][h] = e / s;
    }
    __syncthreads();

    // a[o] = sum_n P[n][h(o)] * V[n][o] + bva[o]
    {
        const int h0 = 2 * wid, h1 = 2 * wid + 1;
        float pa[4];
        #pragma unroll
        for (int j = 0; j < 4; j++) pa[j] = 0.f;
        #pragma unroll
        for (int idx = 0; idx < 4; idx++) {
            const int n0 = q4 * 4 + idx, n1 = 16 + q4 * 4 + idx;
            float p00 = sP[n0][h0], p01 = sP[n0][h1];
            float p10 = sP[n1][h0], p11 = sP[n1][h1];
            pa[0] += p00 * vacc[0][0][idx] + p10 * vacc[1][0][idx];
            pa[1] += p00 * vacc[0][1][idx] + p10 * vacc[1][1][idx];
            pa[2] += p01 * vacc[0][2][idx] + p11 * vacc[1][2][idx];
            pa[3] += p01 * vacc[0][3][idx] + p11 * vacc[1][3][idx];
        }
        #pragma unroll
        for (int j = 0; j < 4; j++) {
            pa[j] += __shfl_xor(pa[j], 16);
            pa[j] += __shfl_xor(pa[j], 32);
        }
        if (q4 == 0) {
            #pragma unroll
            for (int j = 0; j < 4; j++) {
                int o = wid * 64 + j * 16 + l16;
                ag[(size_t)r * 256 + o] = pa[j] + bva[o];
            }
        }
    }
}

// ---------------- kernel C: z-proj, LN, FFN, residual, final LN (verified R1) ----
__global__ __launch_bounds__(256, 2)
void tail_kernel(const float* __restrict__ ag,
                 const float* __restrict__ bp,
                 const float* __restrict__ pre_w, const float* __restrict__ pre_b,
                 const float* __restrict__ b1, const float* __restrict__ b2,
                 const float* __restrict__ post_w, const float* __restrict__ post_b,
                 const unsigned short* __restrict__ wsb,
                 float* __restrict__ out) {
    const int tid  = threadIdx.x;
    const int lane = tid & 63;
    const int wid  = tid >> 6;
    const int q4   = lane >> 4;
    const int l16  = lane & 15;
    const int b    = blockIdx.x >> 8;
    const int m0   = (blockIdx.x & 255) * 16;

    const unsigned short* Wp_bf   = wsb + WPHI_OFF;
    const unsigned short* W1_bf   = wsb + W1_OFF;
    const unsigned short* W2_bf   = wsb + W2_OFF;
    const unsigned short* Wplo_bf = wsb + WPLO_OFF;

    __shared__ __align__(16) float Z[16][260];
    __shared__ __align__(16) unsigned short G[16][520];
    __shared__ __align__(16) unsigned short sQ[16][264];
    __shared__ __align__(16) float sAf[16][260];

    // load a
    #pragma unroll
    for (int rr = 0; rr < 4; rr++) {
        int m = wid * 4 + rr;
        *(float4*)&sAf[m][lane * 4] =
            *(const float4*)(ag + (size_t)(b * 4096 + m0 + m) * 256 + lane * 4);
    }
    __syncthreads();

    // z = sAf @ Wp^T + bp (hi/lo split for accuracy)
    {
        f32x4 acc[4];
        #pragma unroll
        for (int j = 0; j < 4; j++) acc[j] = 0.f;
        #pragma unroll
        for (int k = 0; k < 8; k++) {
            float4 va = *(const float4*)&sAf[l16][k * 32 + q4 * 8];
            float4 vb = *(const float4*)&sAf[l16][k * 32 + q4 * 8 + 4];
            float vs[8] = {va.x, va.y, va.z, va.w, vb.x, vb.y, vb.z, vb.w};
            bf16x8 ah, al;
            #pragma unroll
            for (int j = 0; j < 8; j++) {
                unsigned short hi = f2bf(vs[j]);
                ah[j] = (short)hi;
                al[j] = (short)f2bf(vs[j] - bf2f(hi));
            }
            #pragma unroll
            for (int j = 0; j < 4; j++) {
                bf16x8 bh = *(const bf16x8*)(Wp_bf   + ((((wid * 4 + j) * 8 + k) * 64 + lane) << 3));
                bf16x8 bl = *(const bf16x8*)(Wplo_bf + ((((wid * 4 + j) * 8 + k) * 64 + lane) << 3));
                acc[j] = __builtin_amdgcn_mfma_f32_16x16x32_bf16(ah, bh, acc[j], 0, 0, 0);
                acc[j] = __builtin_amdgcn_mfma_f32_16x16x32_bf16(al, bh, acc[j], 0, 0, 0);
                acc[j] = __builtin_amdgcn_mfma_f32_16x16x32_bf16(ah, bl, acc[j], 0, 0, 0);
            }
        }
        #pragma unroll
        for (int j = 0; j < 4; j++) {
            int o = wid * 64 + j * 16 + l16;
            float bpv = bp[o];
            #pragma unroll
            for (int r = 0; r < 4; r++) Z[q4 * 4 + r][o] = acc[j][r] + bpv;
        }
    }
    __syncthreads();
    // pre-LN: normalize Z in place (residual base) + bf16 copy in sQ
    {
        const float4 w4 = *(const float4*)(pre_w + lane * 4);
        const float4 g4 = *(const float4*)(pre_b + lane * 4);
        #pragma unroll
        for (int rr = 0; rr < 4; rr++) {
            int m = wid * 4 + rr;
            float4 v = *(const float4*)&Z[m][lane * 4];
            float mu, inv; rowstats(v, mu, inv);
            float4 z;
            z.x = (v.x - mu) * inv * w4.x + g4.x;
            z.y = (v.y - mu) * inv * w4.y + g4.y;
            z.z = (v.z - mu) * inv * w4.z + g4.z;
            z.w = (v.w - mu) * inv * w4.w + g4.w;
            *(float4*)&Z[m][lane * 4] = z;
            ushort4 o;
            o.x = f2bf(z.x); o.y = f2bf(z.y); o.z = f2bf(z.z); o.w = f2bf(z.w);
            *(ushort4*)&sQ[m][lane * 4] = o;
        }
    }
    __syncthreads();
    // FFN1 + exact gelu -> G
    {
        f32x4 acc[8];
        #pragma unroll
        for (int j = 0; j < 8; j++) acc[j] = 0.f;
        #pragma unroll
        for (int k = 0; k < 8; k++) {
            bf16x8 af = *(const bf16x8*)&sQ[l16][k * 32 + q4 * 8];
            #pragma unroll
            for (int j = 0; j < 8; j++) {
                bf16x8 bfv = *(const bf16x8*)(W1_bf + ((((wid * 8 + j) * 8 + k) * 64 + lane) << 3));
                acc[j] = __builtin_amdgcn_mfma_f32_16x16x32_bf16(af, bfv, acc[j], 0, 0, 0);
            }
        }
        #pragma unroll
        for (int j = 0; j < 8; j++) {
            int f = wid * 128 + j * 16 + l16;
            float b1v = b1[f];
            #pragma unroll
            for (int r = 0; r < 4; r++) {
                float vz = acc[j][r] + b1v;
                float g = 0.5f * vz * (1.f + erff(vz * 0.7071067811865475f));
                G[q4 * 4 + r][f] = f2bf(g);
            }
        }
    }
    __syncthreads();
    // FFN2 + residual -> Z
    {
        f32x4 acc[4];
        #pragma unroll
        for (int j = 0; j < 4; j++) acc[j] = 0.f;
        #pragma unroll
        for (int k = 0; k < 16; k++) {
            bf16x8 af = *(const bf16x8*)&G[l16][k * 32 + q4 * 8];
            #pragma unroll
            for (int j = 0; j < 4; j++) {
                bf16x8 bfv = *(const bf16x8*)(W2_bf + ((((wid * 4 + j) * 16 + k) * 64 + lane) << 3));
                acc[j] = __builtin_amdgcn_mfma_f32_16x16x32_bf16(af, bfv, acc[j], 0, 0, 0);
            }
        }
        #pragma unroll
        for (int j = 0; j < 4; j++) {
            int o = wid * 64 + j * 16 + l16;
            float b2v = b2[o];
            #pragma unroll
            for (int r = 0; r < 4; r++) Z[q4 * 4 + r][o] += acc[j][r] + b2v;
        }
    }
    __syncthreads();
    // final LN -> out
    {
        const float4 w4 = *(const float4*)(post_w + lane * 4);
        const float4 g4 = *(const float4*)(post_b + lane * 4);
        #pragma unroll
        for (int rr = 0; rr < 4; rr++) {
            int m = wid * 4 + rr;
            float4 v = *(const float4*)&Z[m][lane * 4];
            float mu, inv; rowstats(v, mu, inv);
            float4 o;
            o.x = (v.x - mu) * inv * w4.x + g4.x;
            o.y = (v.y - mu) * inv * w4.y + g4.y;
            o.z = (v.z - mu) * inv * w4.z + g4.z;
            o.w = (v.w - mu) * inv * w4.w + g4.w;
            *(float4*)(out + (size_t)(b * 4096 + m0 + m) * 256 + lane * 4) = o;
        }
    }
}

extern "C" void kernel_launch(void* const* d_in, const int* in_sizes, int n_in,
                              void* d_out, int out_size, void* d_ws, size_t ws_size,
                              hipStream_t stream) {
    (void)in_sizes; (void)n_in; (void)out_size; (void)ws_size;
    const float* x      = (const float*)d_in[0];
    const float* y      = (const float*)d_in[1];
    const float* lnq_w  = (const float*)d_in[2];
    const float* lnq_b  = (const float*)d_in[3];
    const float* Wq     = (const float*)d_in[4];
    const float* bq     = (const float*)d_in[5];
    const float* lnk_w  = (const float*)d_in[6];
    // d_in[7] = lnk_b : softmax-invariant (dropped)
    const float* Wk     = (const float*)d_in[8];
    // d_in[9] = bk : softmax-invariant (dropped)
    const float* lnv_w  = (const float*)d_in[10];
    const float* lnv_b  = (const float*)d_in[11];
    const float* Wv     = (const float*)d_in[12];
    const float* bv     = (const float*)d_in[13];
    const float* Wp     = (const float*)d_in[14];
    const float* bp     = (const float*)d_in[15];
    const float* pre_w  = (const float*)d_in[16];
    const float* pre_b  = (const float*)d_in[17];
    const float* W1     = (const float*)d_in[18];
    const float* b1     = (const float*)d_in[19];
    const float* W2     = (const float*)d_in[20];
    const float* b2     = (const float*)d_in[21];
    const float* post_w = (const float*)d_in[22];
    const float* post_b = (const float*)d_in[23];
    unsigned short* wsb = (unsigned short*)d_ws;
    float* bva = (float*)(wsb + BVA_OFF);
    unsigned short* Tg = wsb + T_OFF;
    float* ag = (float*)(wsb + AG_OFF);

    prep_weights<<<2304, 256, 0, stream>>>(Wq, Wk, Wv, Wp, W1, W2, lnk_w, lnv_w, wsb);
    prep_bias<<<16, 256, 0, stream>>>(Wv, lnv_b, bv, bva);
    qt_kernel<<<512, 256, 0, stream>>>(x, lnq_w, lnq_b, bq, wsb, Tg);
    attn_kernel<<<8192, 256, 0, stream>>>(y, wsb, ag);
    tail_kernel<<<512, 256, 0, stream>>>(ag, bp, pre_w, pre_b, b1, b2, post_w, post_b,
                                         wsb, (float*)d_out);
}